// Round 9
// baseline (67.043 us; speedup 1.0000x reference)
//
#include <hip/hip_runtime.h>
#include <math.h>

// ChamferLoss: B=16, M=N=2048, fp32 2-D points.
// R8 lesson: 1024-thr blocks stall at ~17.5us regardless of DS/VALU counts.
// R5's 512-thr structure is the only one matching its cycle model (19 vs
// 20.5us DS-bound, 93% eff). Keep that structure, halve its DS bottleneck:
//   chip ds_read_b128 = 134M pairs/(2 refs x 64 lanes x QPL)
//   QPL=2 -> 2048 reads/CU x 12cyc = 10.2us DS; VALU 3.5/pair = 6.0us.
// Geometry: 512 thr (8 waves), 128 q/block, wave sweeps 256 refs (128
// uniform b128 reads), grid (16,16,2)=512 blocks = 2/CU = 16 waves/CU.

#define CH_B    16
#define CH_N    2048
#define THREADS 512
#define WAVES   8                     // ref-split factor per block
#define QPL     2                     // queries per lane
#define QPB     (QPL * 64)            // 128 queries per block
#define RPW     (CH_N / WAVES)        // 256 refs per wave slice
#define GRID_X  (CH_N / QPB)          // 16
#define NPART   (GRID_X * CH_B * 2)   // 512 partials

__global__ __launch_bounds__(THREADS, 4) void chamfer_main_kernel(
    const float2* __restrict__ tp, const float2* __restrict__ ap,
    float* __restrict__ partials)
{
    __shared__ float2 spts[CH_N];        // 16 KB staged reference set
    __shared__ float  smin[WAVES][QPB];  // 4 KB per-wave per-query slice maxes
    __shared__ float  ssum[QPL];

    const int tid  = threadIdx.x;
    const int lane = tid & 63;
    const int w    = tid >> 6;
    const int b    = blockIdx.y;
    const int dir  = blockIdx.z;         // 0: target->actual, 1: actual->target

    const float2* q = dir ? ap : tp;
    const float2* r = dir ? tp : ap;

    // 2 queries per lane; doubled coords + q^2 (dot-form).
    const float2* qb = q + (size_t)b * CH_N + blockIdx.x * QPB;
    float Qx0, Qy0, q20, Qx1, Qy1, q21;
    { float2 t = qb[0 * 64 + lane]; Qx0 = 2.f*t.x; Qy0 = 2.f*t.y; q20 = fmaf(t.x,t.x,t.y*t.y); }
    { float2 t = qb[1 * 64 + lane]; Qx1 = 2.f*t.x; Qy1 = 2.f*t.y; q21 = fmaf(t.x,t.x,t.y*t.y); }

    // Stage the full reference set: 512 threads x 2 float4 (2 pts each).
    const float4* rsrc = (const float4*)(r + (size_t)b * CH_N);
    float4* sdst = (float4*)spts;
    #pragma unroll
    for (int k = 0; k < (CH_N / 2) / THREADS; ++k)      // 2 iters
        sdst[tid + k * THREADS] = rsrc[tid + k * THREADS];
    __syncthreads();

    // Sweep this wave's 256-ref slice: 128 wave-uniform b128 reads,
    // 4 refs (2 reads) per step; s = 2 q.p - |p|^2, track max per query.
    const float4* sp4 = (const float4*)spts + w * (RPW / 2);
    float a0 = -3.4e38f, a1 = -3.4e38f, a2 = -3.4e38f, a3 = -3.4e38f;
    #pragma unroll 2
    for (int i = 0; i < RPW / 2; i += 2) {
        float4 p0 = sp4[i + 0];
        float4 p1 = sp4[i + 1];
        float g0 = fmaf(p0.y, p0.y, p0.x * p0.x);
        float g1 = fmaf(p0.w, p0.w, p0.z * p0.z);
        float g2 = fmaf(p1.y, p1.y, p1.x * p1.x);
        float g3 = fmaf(p1.w, p1.w, p1.z * p1.z);
        float sa, sb, sc, sd;
        // query 0 (accs a0/a2 alternate for ILP)
        sa = fmaf(Qx0, p0.x, fmaf(Qy0, p0.y, -g0));
        sb = fmaf(Qx0, p0.z, fmaf(Qy0, p0.w, -g1));
        sc = fmaf(Qx0, p1.x, fmaf(Qy0, p1.y, -g2));
        sd = fmaf(Qx0, p1.z, fmaf(Qy0, p1.w, -g3));
        a0 = fmaxf(fmaxf(a0, sa), sb);               // -> v_max3
        a2 = fmaxf(fmaxf(a2, sc), sd);
        // query 1
        sa = fmaf(Qx1, p0.x, fmaf(Qy1, p0.y, -g0));
        sb = fmaf(Qx1, p0.z, fmaf(Qy1, p0.w, -g1));
        sc = fmaf(Qx1, p1.x, fmaf(Qy1, p1.y, -g2));
        sd = fmaf(Qx1, p1.z, fmaf(Qy1, p1.w, -g3));
        a1 = fmaxf(fmaxf(a1, sa), sb);
        a3 = fmaxf(fmaxf(a3, sc), sd);
    }
    smin[w][0 * 64 + lane] = fmaxf(a0, a2);
    smin[w][1 * 64 + lane] = fmaxf(a1, a3);
    __syncthreads();

    // Waves 0..1: wave j combines the 8 ref-slices for query row j,
    // d = sqrt(q^2 - s_max), then wave-sum.
    if (w < QPL) {
        float v = smin[0][w * 64 + lane];
        #pragma unroll
        for (int ww = 1; ww < WAVES; ++ww)
            v = fmaxf(v, smin[ww][w * 64 + lane]);   // 64 consec floats: free
        float q2 = (w == 0) ? q20 : q21;
        v = sqrtf(fmaxf(q2 - v, 0.f));
        #pragma unroll
        for (int off = 1; off < 64; off <<= 1)
            v += __shfl_xor(v, off);
        if (lane == 0) ssum[w] = v;
    }
    __syncthreads();
    if (tid == 0)
        partials[((size_t)dir * CH_B + b) * GRID_X + blockIdx.x] =
            ssum[0] + ssum[1];
}

__global__ __launch_bounds__(64) void chamfer_reduce_kernel(
    const float* __restrict__ partials, float* __restrict__ out, float scale)
{
    const int tid = threadIdx.x;
    const float4* p4 = (const float4*)partials;   // 512 floats = 128 float4
    float4 v0 = p4[tid];
    float4 v1 = p4[tid + 64];
    float s = v0.x + v0.y + v0.z + v0.w + v1.x + v1.y + v1.z + v1.w;
    #pragma unroll
    for (int off = 1; off < 64; off <<= 1)
        s += __shfl_xor(s, off);
    if (tid == 0) out[0] = s * scale;
}

extern "C" void kernel_launch(void* const* d_in, const int* in_sizes, int n_in,
                              void* d_out, int out_size, void* d_ws, size_t ws_size,
                              hipStream_t stream) {
    const float2* tp = (const float2*)d_in[0];  // target_points [B, M, 2]
    const float2* ap = (const float2*)d_in[1];  // actual_points [B, N, 2]
    float* out      = (float*)d_out;
    float* partials = (float*)d_ws;             // 512 floats, fully overwritten

    dim3 grid(GRID_X, CH_B, 2);                 // 512 blocks x 512 threads
    chamfer_main_kernel<<<grid, THREADS, 0, stream>>>(tp, ap, partials);

    const float scale = 1.0f / (float)(CH_B * CH_N);   // M == N == 2048
    chamfer_reduce_kernel<<<1, 64, 0, stream>>>(partials, out, scale);
}

// Round 11
// 65.700 us; speedup vs baseline: 1.0205x; 1.0205x over previous
//
#include <hip/hip_runtime.h>
#include <math.h>

// ChamferLoss: B=16, M=N=2048, fp32 2-D points.
// Best structure = R8 (dur 65.5): 1024-thr blocks, 16 waves, QPL=4, dot-form
//   min_n d2 = q^2 - max_n s,  s = 2(q.p) - |p|^2   (2.75 VALU/pair)
// Cross-round finding: 5 structures all land 17.5-20.5us main => effective
// burst clock ~1.2 GHz (DVFS never ramps in a 20us kernel after a 40us
// memory-bound fill). R8 residual ~4us vs model: suspect per-step lgkmcnt
// lockstep (16 barrier-synced waves). This round: 2-stage software pipeline
// (issue next step's 2 ds_read_b128 before computing current step).

#define CH_B    16
#define CH_N    2048
#define THREADS 1024
#define WAVES   16                    // ref-split factor
#define QPL     4                     // queries per lane
#define QPB     (QPL * 64)            // 256 queries per block
#define RPW     (CH_N / WAVES)        // 128 refs per wave slice
#define GRID_X  (CH_N / QPB)          // 8
#define NPART   (GRID_X * CH_B * 2)   // 256 partials

__global__ __launch_bounds__(THREADS, 4) void chamfer_main_kernel(
    const float2* __restrict__ tp, const float2* __restrict__ ap,
    float* __restrict__ partials)
{
    __shared__ float2 spts[CH_N];        // 16 KB staged reference set
    __shared__ float  smin[WAVES][QPB];  // 16 KB per-wave per-query slice maxes
    __shared__ float  ssum[QPL];

    const int tid  = threadIdx.x;
    const int lane = tid & 63;
    const int w    = tid >> 6;
    const int b    = blockIdx.y;
    const int dir  = blockIdx.z;         // 0: target->actual, 1: actual->target

    const float2* q = dir ? ap : tp;
    const float2* r = dir ? tp : ap;

    // 4 queries per lane; doubled coords + q^2 (dot-form).
    const float2* qb = q + (size_t)b * CH_N + blockIdx.x * QPB;
    float Qx0, Qy0, q20, Qx1, Qy1, q21, Qx2, Qy2, q22, Qx3, Qy3, q23;
    { float2 t = qb[0 * 64 + lane]; Qx0 = 2.f*t.x; Qy0 = 2.f*t.y; q20 = fmaf(t.x,t.x,t.y*t.y); }
    { float2 t = qb[1 * 64 + lane]; Qx1 = 2.f*t.x; Qy1 = 2.f*t.y; q21 = fmaf(t.x,t.x,t.y*t.y); }
    { float2 t = qb[2 * 64 + lane]; Qx2 = 2.f*t.x; Qy2 = 2.f*t.y; q22 = fmaf(t.x,t.x,t.y*t.y); }
    { float2 t = qb[3 * 64 + lane]; Qx3 = 2.f*t.x; Qy3 = 2.f*t.y; q23 = fmaf(t.x,t.x,t.y*t.y); }

    // Stage the full reference set: 1024 threads x 1 float4 (2 pts each).
    ((float4*)spts)[tid] = ((const float4*)(r + (size_t)b * CH_N))[tid];
    __syncthreads();

    // Sweep this wave's 128-ref slice: 64 wave-uniform b128 reads, 4 refs
    // (2 reads) per step, 2-stage software pipeline: next step's reads are
    // issued before current step's 44-VALU body so DS latency hides under
    // compute instead of lockstep load->lgkmcnt(0)->compute.
    const float4* sp4 = (const float4*)spts + w * (RPW / 2);
    float a0 = -3.4e38f, a1 = -3.4e38f, a2 = -3.4e38f, a3 = -3.4e38f;

    float4 c0 = sp4[0];
    float4 c1 = sp4[1];
    #pragma unroll 2
    for (int i = 2; i <= RPW / 2; i += 2) {
        // Prefetch next step (guarded; last iteration reuses current).
        float4 n0, n1;
        if (i < RPW / 2) { n0 = sp4[i]; n1 = sp4[i + 1]; }

        float g0 = fmaf(c0.y, c0.y, c0.x * c0.x);
        float g1 = fmaf(c0.w, c0.w, c0.z * c0.z);
        float g2 = fmaf(c1.y, c1.y, c1.x * c1.x);
        float g3 = fmaf(c1.w, c1.w, c1.z * c1.z);
        float sa, sb, sc, sd;
        // query 0
        sa = fmaf(Qx0, c0.x, fmaf(Qy0, c0.y, -g0));
        sb = fmaf(Qx0, c0.z, fmaf(Qy0, c0.w, -g1));
        sc = fmaf(Qx0, c1.x, fmaf(Qy0, c1.y, -g2));
        sd = fmaf(Qx0, c1.z, fmaf(Qy0, c1.w, -g3));
        a0 = fmaxf(fmaxf(a0, sa), sb);               // -> v_max3
        a0 = fmaxf(fmaxf(a0, sc), sd);
        // query 1
        sa = fmaf(Qx1, c0.x, fmaf(Qy1, c0.y, -g0));
        sb = fmaf(Qx1, c0.z, fmaf(Qy1, c0.w, -g1));
        sc = fmaf(Qx1, c1.x, fmaf(Qy1, c1.y, -g2));
        sd = fmaf(Qx1, c1.z, fmaf(Qy1, c1.w, -g3));
        a1 = fmaxf(fmaxf(a1, sa), sb);
        a1 = fmaxf(fmaxf(a1, sc), sd);
        // query 2
        sa = fmaf(Qx2, c0.x, fmaf(Qy2, c0.y, -g0));
        sb = fmaf(Qx2, c0.z, fmaf(Qy2, c0.w, -g1));
        sc = fmaf(Qx2, c1.x, fmaf(Qy2, c1.y, -g2));
        sd = fmaf(Qx2, c1.z, fmaf(Qy2, c1.w, -g3));
        a2 = fmaxf(fmaxf(a2, sa), sb);
        a2 = fmaxf(fmaxf(a2, sc), sd);
        // query 3
        sa = fmaf(Qx3, c0.x, fmaf(Qy3, c0.y, -g0));
        sb = fmaf(Qx3, c0.z, fmaf(Qy3, c0.w, -g1));
        sc = fmaf(Qx3, c1.x, fmaf(Qy3, c1.y, -g2));
        sd = fmaf(Qx3, c1.z, fmaf(Qy3, c1.w, -g3));
        a3 = fmaxf(fmaxf(a3, sa), sb);
        a3 = fmaxf(fmaxf(a3, sc), sd);

        c0 = n0; c1 = n1;
    }
    smin[w][0 * 64 + lane] = a0;
    smin[w][1 * 64 + lane] = a1;
    smin[w][2 * 64 + lane] = a2;
    smin[w][3 * 64 + lane] = a3;
    __syncthreads();

    // Waves 0..3: wave j combines the 16 ref-slices for query row j,
    // d = sqrt(q^2 - s_max), then wave-sum.
    if (w < QPL) {
        float v = smin[0][w * 64 + lane];
        #pragma unroll
        for (int ww = 1; ww < WAVES; ++ww)
            v = fmaxf(v, smin[ww][w * 64 + lane]);
        float q2 = (w == 0) ? q20 : (w == 1) ? q21 : (w == 2) ? q22 : q23;
        v = sqrtf(fmaxf(q2 - v, 0.f));
        #pragma unroll
        for (int off = 1; off < 64; off <<= 1)
            v += __shfl_xor(v, off);
        if (lane == 0) ssum[w] = v;
    }
    __syncthreads();
    if (tid == 0)
        partials[((size_t)dir * CH_B + b) * GRID_X + blockIdx.x] =
            ssum[0] + ssum[1] + ssum[2] + ssum[3];
}

__global__ __launch_bounds__(64) void chamfer_reduce_kernel(
    const float* __restrict__ partials, float* __restrict__ out, float scale)
{
    const int tid = threadIdx.x;
    const float4* p4 = (const float4*)partials;   // 256 floats = 64 float4
    float4 v = p4[tid];
    float s = v.x + v.y + v.z + v.w;
    #pragma unroll
    for (int off = 1; off < 64; off <<= 1)
        s += __shfl_xor(s, off);
    if (tid == 0) out[0] = s * scale;
}

extern "C" void kernel_launch(void* const* d_in, const int* in_sizes, int n_in,
                              void* d_out, int out_size, void* d_ws, size_t ws_size,
                              hipStream_t stream) {
    const float2* tp = (const float2*)d_in[0];  // target_points [B, M, 2]
    const float2* ap = (const float2*)d_in[1];  // actual_points [B, N, 2]
    float* out      = (float*)d_out;
    float* partials = (float*)d_ws;             // 256 floats, fully overwritten

    dim3 grid(GRID_X, CH_B, 2);                 // 256 blocks x 1024 threads
    chamfer_main_kernel<<<grid, THREADS, 0, stream>>>(tp, ap, partials);

    const float scale = 1.0f / (float)(CH_B * CH_N);   // M == N == 2048
    chamfer_reduce_kernel<<<1, 64, 0, stream>>>(partials, out, scale);
}